// Round 7
// baseline (338.865 us; speedup 1.0000x reference)
//
#include <hip/hip_runtime.h>
#include <hip/hip_bf16.h>

typedef __attribute__((ext_vector_type(8))) short bf16x8;
typedef __attribute__((ext_vector_type(4))) float f32x4;

#define LOG2E 1.44269504088896340736f
#define MAGIC 0x13572468u

// ---- workspace layout ----
// bf16 element offsets
#define QB_OFF 2621440
#define KB_OFF 3145728
#define VT_OFF 3670016
#define AO_OFF 4194304
#define WQ_OFF 1572864   // unused (kept for layout stability)
// byte offsets (fp32 tables / seg indices / sync)
#define T_B   9437184
#define A_B   (T_B + 4096)
#define C_B   (A_B + 20480)
#define SEG_B (C_B + 20480)
#define FLAG_B (SEG_B + 1048576)
#define CNT_B  (FLAG_B + 64)

struct MegaArgs {
  const float *xq, *xk, *xv, *eg;
  const float *wq, *wk, *wv, *wo;
  const float *bq, *bk, *bv, *bo;
  const float *w1, *b1, *we2, *be2;
  float* out;
  unsigned short* wsb;
  float *wsT, *wsA, *wsC;   // wsA/wsC stored [h][513] for coalesced attn loads
  unsigned short* segp;
  unsigned int *flag, *cnt;
};

__device__ __forceinline__ unsigned short f2bf(float f) {
  union { __hip_bfloat16 h; unsigned short u; } c;
  c.h = __float2bfloat16(f);
  return c.u;
}

__device__ __forceinline__ uint4 pack8(float4 a, float4 b) {
  union { unsigned short us[8]; uint4 u; } r;
  r.us[0] = f2bf(a.x); r.us[1] = f2bf(a.y); r.us[2] = f2bf(a.z); r.us[3] = f2bf(a.w);
  r.us[4] = f2bf(b.x); r.us[5] = f2bf(b.y); r.us[6] = f2bf(b.z); r.us[7] = f2bf(b.w);
  return r.u;
}

// ---------------- edge-MLP -> exact PWL tables (1 block, 256 threads) ----------------
// f_h(e) = sum_k We2[k,h]*relu(e*w1[k]+b1[k]) + be2[h] is PWL with breakpoints t_k=-b1/w1.
__device__ void prep_block(const MegaArgs& a, char* smem) {
  float* sT   = (float*)smem;                      // 2048
  int*   sIdx = (int*)(smem + 2048);               // 2048
  float (*sDA)[8] = (float (*)[8])(smem + 4096);   // 16384
  float (*sDC)[8] = (float (*)[8])(smem + 20480);  // 16384
  float* sA0 = (float*)(smem + 36864);             // 32
  float* sC0 = (float*)(smem + 36896);             // 32
  int tid = threadIdx.x;
  for (int p = tid; p < 512; p += 256) {
    float w = a.w1[p], bb = a.b1[p];
    sT[p] = (w != 0.f) ? (-bb / w) : -3.4e38f;  // w==0: never a real crossing
    sIdx[p] = p;
#pragma unroll
    for (int h = 0; h < 8; ++h) {
      float w2 = a.we2[p * 8 + h];
      float ra = 0.f, rc = 0.f;
      if (w < 0.f)       { ra = w2 * w; rc = w2 * bb; }
      else if (w == 0.f) { rc = w2 * fmaxf(bb, 0.f); }
      sDA[p][h] = ra; sDC[p][h] = rc;
    }
  }
  __syncthreads();
  // bitonic sort ascending: 256 compare-exchange pairs per substage
  for (int size = 2; size <= 512; size <<= 1) {
    for (int stride = size >> 1; stride > 0; stride >>= 1) {
      int p = tid;
      int i = ((p / stride) * (stride << 1)) + (p % stride);
      int j = i + stride;
      bool up = ((i & size) == 0);
      float ti = sT[i], tj = sT[j];
      if (up ? (ti > tj) : (ti < tj)) {
        sT[i] = tj; sT[j] = ti;
        int t = sIdx[i]; sIdx[i] = sIdx[j]; sIdx[j] = t;
      }
      __syncthreads();
    }
  }
  // tree-reduce seg0 contributions
#pragma unroll
  for (int h = 0; h < 8; ++h) { sDA[tid][h] += sDA[tid + 256][h]; sDC[tid][h] += sDC[tid + 256][h]; }
  __syncthreads();
  for (int st = 128; st > 0; st >>= 1) {
    if (tid < st) {
#pragma unroll
      for (int h = 0; h < 8; ++h) { sDA[tid][h] += sDA[tid + st][h]; sDC[tid][h] += sDC[tid + st][h]; }
    }
    __syncthreads();
  }
  if (tid < 8) { sA0[tid] = sDA[0][tid]; sC0[tid] = sDC[0][tid] + a.be2[tid]; }
  __syncthreads();
  // per-sorted-position deltas
  for (int p = tid; p < 512; p += 256) {
    int k = sIdx[p];
    float wk = a.w1[k], bk2 = a.b1[k];
#pragma unroll
    for (int h = 0; h < 8; ++h) {
      float w2 = a.we2[k * 8 + h];
      float da = 0.f, dc = 0.f;
      if (wk > 0.f)      { da =  w2 * wk; dc =  w2 * bk2; }
      else if (wk < 0.f) { da = -w2 * wk; dc = -w2 * bk2; }
      sDA[p][h] = da; sDC[p][h] = dc;
    }
  }
  __syncthreads();
  // inclusive Hillis-Steele scan over 512 sorted positions, 2 per thread
  for (int off = 1; off < 512; off <<= 1) {
    float ra[2][8], rc[2][8];
#pragma unroll
    for (int e = 0; e < 2; ++e) {
      int p = tid + e * 256;
      if (p >= off) {
#pragma unroll
        for (int h = 0; h < 8; ++h) { ra[e][h] = sDA[p - off][h]; rc[e][h] = sDC[p - off][h]; }
      }
    }
    __syncthreads();
#pragma unroll
    for (int e = 0; e < 2; ++e) {
      int p = tid + e * 256;
      if (p >= off) {
#pragma unroll
        for (int h = 0; h < 8; ++h) { sDA[p][h] += ra[e][h]; sDC[p][h] += rc[e][h]; }
      }
    }
    __syncthreads();
  }
  a.wsT[tid] = sT[tid]; a.wsT[tid + 256] = sT[tid + 256];
  if (tid < 8) { a.wsA[tid * 513] = sA0[tid]; a.wsC[tid * 513] = sC0[tid]; }
  for (int p = tid; p < 512; p += 256) {
#pragma unroll
    for (int h = 0; h < 8; ++h) {
      a.wsA[h * 513 + p + 1] = sA0[h] + sDA[p][h];
      a.wsC[h * 513 + p + 1] = sC0[h] + sDC[p][h];
    }
  }
}

// ---------------- per-edge segment index: fixed 9-step branchless lower-bound ---------
__device__ void seg_block(const MegaArgs& a, int sblk, char* smem) {
  float* sT = (float*)smem;
  int tid = threadIdx.x;
  sT[tid] = a.wsT[tid]; sT[tid + 256] = a.wsT[tid + 256];
  __syncthreads();
  int base = sblk * 1024;
  float ev[4];
#pragma unroll
  for (int j = 0; j < 4; ++j) ev[j] = a.eg[base + j * 256 + tid];
  int res[4];
#pragma unroll
  for (int j = 0; j < 4; ++j) {
    int lo = 0, hi = 512;
#pragma unroll
    for (int it = 0; it < 9; ++it) {
      int mid = (lo + hi) >> 1;
      bool c = sT[mid] < ev[j];
      lo = c ? mid + 1 : lo;
      hi = c ? hi : mid;
    }
    res[j] = lo;
  }
#pragma unroll
  for (int j = 0; j < 4; ++j) a.segp[base + j * 256 + tid] = (unsigned short)res[j];
}

// ---------------- bf16 MFMA GEMM tile with in-staging fp32 convert/transpose ----------
// A: fp32 (Af) or bf16 (Ab), row-major [M][512]. W: fp32 [512][N] row-major, transposed
// to bf16 during LDS staging. Y = A @ W + bias (64x64 tile, K=512).
__device__ void gemm_core(const float* __restrict__ Af, const unsigned short* __restrict__ Ab,
                          const float* __restrict__ W, const float* __restrict__ bias,
                          void* out, int mode, int m0, int n0, char* smem) {
  unsigned short (*sA)[72]  = (unsigned short (*)[72])smem;
  unsigned short (*sBt)[72] = (unsigned short (*)[72])(smem + 9216);
  int tid = threadIdx.x, wave = tid >> 6, lane = tid & 63;
  int quad = lane >> 4, l16 = lane & 15;
  f32x4 acc[4] = {{0.f,0.f,0.f,0.f},{0.f,0.f,0.f,0.f},{0.f,0.f,0.f,0.f},{0.f,0.f,0.f,0.f}};
  int lr = tid >> 2, ls = tid & 3;
  for (int kb = 0; kb < 512; kb += 64) {
    __syncthreads();
    if (Af) {
      const float4* ap = (const float4*)(Af + (size_t)(m0 + lr) * 512 + kb + ls * 16);
      float4 v0 = ap[0], v1 = ap[1], v2 = ap[2], v3 = ap[3];
      *(uint4*)&sA[lr][ls * 16]     = pack8(v0, v1);
      *(uint4*)&sA[lr][ls * 16 + 8] = pack8(v2, v3);
    } else {
      *(uint4*)&sA[lr][ls * 16]     = *(const uint4*)(Ab + (size_t)(m0 + lr) * 512 + kb + ls * 16);
      *(uint4*)&sA[lr][ls * 16 + 8] = *(const uint4*)(Ab + (size_t)(m0 + lr) * 512 + kb + ls * 16 + 8);
    }
    {
      // W[kb+lr][n0+ls*16 .. +16] fp32 -> sBt[n][k] bf16 (scalar transpose writes)
      const float4* wp = (const float4*)(W + (size_t)(kb + lr) * 512 + n0 + ls * 16);
      float4 w0 = wp[0], w1 = wp[1], w2 = wp[2], w3 = wp[3];
      int nb = ls * 16;
      sBt[nb + 0][lr] = f2bf(w0.x);  sBt[nb + 1][lr] = f2bf(w0.y);
      sBt[nb + 2][lr] = f2bf(w0.z);  sBt[nb + 3][lr] = f2bf(w0.w);
      sBt[nb + 4][lr] = f2bf(w1.x);  sBt[nb + 5][lr] = f2bf(w1.y);
      sBt[nb + 6][lr] = f2bf(w1.z);  sBt[nb + 7][lr] = f2bf(w1.w);
      sBt[nb + 8][lr] = f2bf(w2.x);  sBt[nb + 9][lr] = f2bf(w2.y);
      sBt[nb + 10][lr] = f2bf(w2.z); sBt[nb + 11][lr] = f2bf(w2.w);
      sBt[nb + 12][lr] = f2bf(w3.x); sBt[nb + 13][lr] = f2bf(w3.y);
      sBt[nb + 14][lr] = f2bf(w3.z); sBt[nb + 15][lr] = f2bf(w3.w);
    }
    __syncthreads();
    for (int ks = 0; ks < 2; ++ks) {
      bf16x8 af = *(const bf16x8*)&sA[wave * 16 + l16][ks * 32 + quad * 8];
#pragma unroll
      for (int nt = 0; nt < 4; ++nt) {
        bf16x8 bf = *(const bf16x8*)&sBt[nt * 16 + l16][ks * 32 + quad * 8];
        acc[nt] = __builtin_amdgcn_mfma_f32_16x16x32_bf16(af, bf, acc[nt], 0, 0, 0);
      }
    }
  }
  int mbase = m0 + wave * 16 + quad * 4;  // C row = quad*4+reg (m89-verified)
#pragma unroll
  for (int nt = 0; nt < 4; ++nt) {
    int n = n0 + nt * 16 + l16;
    float bv = bias[n];
#pragma unroll
    for (int r = 0; r < 4; ++r) {
      float v = acc[nt][r] + bv;
      int m = mbase + r;
      if (mode == 0) {
        int b = m >> 9, l = m & 511, hh = n >> 6, d = n & 63;
        ((unsigned short*)out)[(((size_t)(b * 8 + hh) * 512) + l) * 64 + d] = f2bf(v);
      } else if (mode == 1) {
        ((float*)out)[(size_t)m * 512 + n] = v;
      } else {
        int b = m >> 9, l = m & 511, hh = n >> 6, d = n & 63;
        ((unsigned short*)out)[(((size_t)(b * 8 + hh) * 64) + d) * 512 + l] = f2bf(v);
      }
    }
  }
}

// ---------------- fused edge-bias attention (16 q-rows/block, waves split keys) -------
__device__ void attn_block(const MegaArgs& a, int qt, int h, int b, char* smem) {
  float* sAh = (float*)smem;                                            // 2052
  float* sCh = (float*)(smem + 2052);                                   // 2052
  unsigned short (*sP)[16][40] = (unsigned short (*)[16][40])(smem + 4112);  // 5120
  float (*sO)[4][16][16] = (float (*)[4][16][16])(smem + 9232);         // 16384
  float (*sM)[16] = (float (*)[16])(smem + 25616);                      // 256
  float (*sL)[16] = (float (*)[16])(smem + 25872);                      // 256
  const unsigned short* Qb = a.wsb + QB_OFF;
  const unsigned short* Kb = a.wsb + KB_OFF;
  const unsigned short* Vt = a.wsb + VT_OFF;
  int bh = b * 8 + h;
  int q0 = qt * 16;
  int tid = threadIdx.x, wave = tid >> 6, lane = tid & 63;
  int quad = lane >> 4, l16 = lane & 15;
  for (int i = tid; i < 513; i += 256) { sAh[i] = a.wsA[h * 513 + i]; sCh[i] = a.wsC[h * 513 + i]; }
  const unsigned short* qp = Qb + ((size_t)bh * 512 + q0 + l16) * 64 + quad * 8;
  bf16x8 qf0 = *(const bf16x8*)qp;
  bf16x8 qf1 = *(const bf16x8*)(qp + 32);
  int key_base = wave * 128;
  f32x4 S[4][2];
#pragma unroll
  for (int kt = 0; kt < 4; ++kt) {
    int key0 = key_base + kt * 32;
#pragma unroll
    for (int half = 0; half < 2; ++half) {
      const unsigned short* kp = Kb + ((size_t)bh * 512 + key0 + half * 16 + l16) * 64 + quad * 8;
      bf16x8 kf0 = *(const bf16x8*)kp;
      bf16x8 kf1 = *(const bf16x8*)(kp + 32);
      f32x4 acc = {0.f, 0.f, 0.f, 0.f};
      acc = __builtin_amdgcn_mfma_f32_16x16x32_bf16(qf0, kf0, acc, 0, 0, 0);
      acc = __builtin_amdgcn_mfma_f32_16x16x32_bf16(qf1, kf1, acc, 0, 0, 0);
      S[kt][half] = acc;
    }
  }
  __syncthreads();  // sAh/sCh ready
#pragma unroll
  for (int kt = 0; kt < 4; ++kt)
#pragma unroll
    for (int half = 0; half < 2; ++half)
#pragma unroll
      for (int r = 0; r < 4; ++r) {
        int eidx = (b * 512 + q0 + quad * 4 + r) * 512 + key_base + kt * 32 + half * 16 + l16;
        float ev = a.eg[eidx];
        int sg = a.segp[eidx];
        S[kt][half][r] = S[kt][half][r] * 0.125f + sAh[sg] * ev + sCh[sg];
      }
  float m_w[4], l_w[4];
#pragma unroll
  for (int r = 0; r < 4; ++r) {
    float mx = -3.4e38f;
#pragma unroll
    for (int kt = 0; kt < 4; ++kt) { mx = fmaxf(mx, fmaxf(S[kt][0][r], S[kt][1][r])); }
    for (int off = 1; off < 16; off <<= 1) mx = fmaxf(mx, __shfl_xor(mx, off, 64));
    float s = 0.f;
#pragma unroll
    for (int kt = 0; kt < 4; ++kt)
#pragma unroll
      for (int half = 0; half < 2; ++half) {
        float p = exp2f((S[kt][half][r] - mx) * LOG2E);
        S[kt][half][r] = p; s += p;
      }
    for (int off = 1; off < 16; off <<= 1) s += __shfl_xor(s, off, 64);
    m_w[r] = mx; l_w[r] = s;
  }
  f32x4 Oacc[4] = {{0.f,0.f,0.f,0.f},{0.f,0.f,0.f,0.f},{0.f,0.f,0.f,0.f},{0.f,0.f,0.f,0.f}};
#pragma unroll
  for (int kt = 0; kt < 4; ++kt) {
    int key0 = key_base + kt * 32;
#pragma unroll
    for (int half = 0; half < 2; ++half)
#pragma unroll
      for (int r = 0; r < 4; ++r)
        sP[wave][quad * 4 + r][half * 16 + l16] = f2bf(S[kt][half][r]);
    __builtin_amdgcn_wave_barrier();  // wave-private LDS; compiler fence only
    bf16x8 pf = *(const bf16x8*)&sP[wave][l16][quad * 8];
    __builtin_amdgcn_wave_barrier();
#pragma unroll
    for (int nt = 0; nt < 4; ++nt) {
      bf16x8 vf = *(const bf16x8*)(Vt + ((size_t)bh * 64 + nt * 16 + l16) * 512 + key0 + quad * 8);
      Oacc[nt] = __builtin_amdgcn_mfma_f32_16x16x32_bf16(pf, vf, Oacc[nt], 0, 0, 0);
    }
  }
  if (l16 == 0) {
#pragma unroll
    for (int r = 0; r < 4; ++r) { sM[wave][quad * 4 + r] = m_w[r]; sL[wave][quad * 4 + r] = l_w[r]; }
  }
#pragma unroll
  for (int nt = 0; nt < 4; ++nt)
#pragma unroll
    for (int r = 0; r < 4; ++r)
      sO[wave][nt][quad * 4 + r][l16] = Oacc[nt][r];
  __syncthreads();
#pragma unroll
  for (int r = 0; r < 4; ++r) {
    int row = quad * 4 + r;
    float M = fmaxf(fmaxf(sM[0][row], sM[1][row]), fmaxf(sM[2][row], sM[3][row]));
    float L = 0.f, Ov = 0.f;
#pragma unroll
    for (int wv = 0; wv < 4; ++wv) {
      float f = exp2f((sM[wv][row] - M) * LOG2E);
      L += f * sL[wv][row];
      Ov += f * sO[wv][wave][row][l16];
    }
    float v = Ov / L;
    (a.wsb + AO_OFF)[((size_t)(b * 512 + q0 + row)) * 512 + h * 64 + wave * 16 + l16] = f2bf(v);
  }
}

// ---------------- launch 1: prep + QKV GEMM (fp32-direct) + seg (flag-spin) -----------
__global__ __launch_bounds__(256) void k_head(MegaArgs a) {
  __shared__ __align__(16) char smem[36928];
  int blk = blockIdx.x, tid = threadIdx.x;
  if (blk == 0) {
    if (tid == 0) __hip_atomic_store(a.cnt, 0u, __ATOMIC_RELAXED, __HIP_MEMORY_SCOPE_AGENT);
    prep_block(a, smem);
    __threadfence();
    __syncthreads();
    if (tid == 0) __hip_atomic_store(a.flag, MAGIC, __ATOMIC_RELEASE, __HIP_MEMORY_SCOPE_AGENT);
  } else if (blk <= 384) {
    int g = blk - 1, z = g >> 7, rem = g & 127;
    const float* A    = (z == 0) ? a.xq : (z == 1) ? a.xk : a.xv;
    const float* W    = (z == 0) ? a.wq : (z == 1) ? a.wk : a.wv;
    const float* bias = (z == 0) ? a.bq : (z == 1) ? a.bk : a.bv;
    void* outp = (void*)(a.wsb + ((z == 0) ? QB_OFF : (z == 1) ? KB_OFF : VT_OFF));
    gemm_core(A, nullptr, W, bias, outp, (z == 2) ? 2 : 0, (rem & 15) * 64, (rem >> 4) * 64, smem);
  } else {
    if (tid == 0) {
      while (__hip_atomic_load(a.flag, __ATOMIC_ACQUIRE, __HIP_MEMORY_SCOPE_AGENT) != MAGIC)
        __builtin_amdgcn_s_sleep(8);
    }
    __syncthreads();
    seg_block(a, blk - 385, smem);
  }
}

// ---------------- launch 2: attention (counter-release) + output GEMM (counter-spin) --
__global__ __launch_bounds__(256) void k_tail(MegaArgs a) {
  __shared__ __align__(16) char smem[26128];
  int blk = blockIdx.x, tid = threadIdx.x;
  if (blk < 512) {
    attn_block(a, blk & 31, (blk >> 5) & 7, blk >> 8, smem);
    __threadfence();
    __syncthreads();
    if (tid == 0) __hip_atomic_fetch_add(a.cnt, 1u, __ATOMIC_RELEASE, __HIP_MEMORY_SCOPE_AGENT);
  } else {
    if (tid == 0) {
      // >= (not ==): hang-proof under rocprof single-dispatch replay with poisoned cnt
      while (__hip_atomic_load(a.cnt, __ATOMIC_ACQUIRE, __HIP_MEMORY_SCOPE_AGENT) < 512u)
        __builtin_amdgcn_s_sleep(8);
    }
    __syncthreads();
    __threadfence();
    int g = blk - 512;
    gemm_core(nullptr, a.wsb + AO_OFF, a.wo, a.bo, (void*)a.out, 1,
              (g & 15) * 64, (g >> 4) * 64, smem);
  }
}

extern "C" void kernel_launch(void* const* d_in, const int* in_sizes, int n_in,
                              void* d_out, int out_size, void* d_ws, size_t ws_size,
                              hipStream_t stream) {
  MegaArgs a;
  a.xq  = (const float*)d_in[0];
  a.xk  = (const float*)d_in[1];
  a.xv  = (const float*)d_in[2];
  a.eg  = (const float*)d_in[3];
  a.wq  = (const float*)d_in[4];
  a.bq  = (const float*)d_in[5];
  a.wk  = (const float*)d_in[6];
  a.bk  = (const float*)d_in[7];
  a.wv  = (const float*)d_in[8];
  a.bv  = (const float*)d_in[9];
  a.wo  = (const float*)d_in[10];
  a.bo  = (const float*)d_in[11];
  a.w1  = (const float*)d_in[12];
  a.b1  = (const float*)d_in[13];
  a.we2 = (const float*)d_in[14];
  a.be2 = (const float*)d_in[15];
  a.out = (float*)d_out;
  a.wsb = (unsigned short*)d_ws;
  a.wsT = (float*)((char*)d_ws + T_B);
  a.wsA = (float*)((char*)d_ws + A_B);
  a.wsC = (float*)((char*)d_ws + C_B);
  a.segp = (unsigned short*)((char*)d_ws + SEG_B);
  a.flag = (unsigned int*)((char*)d_ws + FLAG_B);
  a.cnt  = (unsigned int*)((char*)d_ws + CNT_B);

  k_head<<<897, 256, 0, stream>>>(a);
  k_tail<<<640, 256, 0, stream>>>(a);
}

// Round 8
// 139.278 us; speedup vs baseline: 2.4330x; 2.4330x over previous
//
#include <hip/hip_runtime.h>
#include <hip/hip_bf16.h>

typedef __attribute__((ext_vector_type(8))) short bf16x8;
typedef __attribute__((ext_vector_type(4))) float f32x4;

#define LOG2E 1.44269504088896340736f

// ---- workspace layout ----
// bf16 element offsets
#define QB_OFF 2621440
#define KB_OFF 3145728
#define VT_OFF 3670016
#define AO_OFF 4194304
// byte offsets (fp32 tables)
#define T_B   9437184
#define A_B   (T_B + 4096)
#define C_B   (A_B + 20480)

struct MegaArgs {
  const float *xq, *xk, *xv, *eg;
  const float *wq, *wk, *wv, *wo;
  const float *bq, *bk, *bv, *bo;
  const float *w1, *b1, *we2, *be2;
  float* out;
  unsigned short* wsb;
  float *wsT, *wsA, *wsC;   // wsA/wsC stored [h][513] for coalesced attn loads
};

__device__ __forceinline__ unsigned short f2bf(float f) {
  union { __hip_bfloat16 h; unsigned short u; } c;
  c.h = __float2bfloat16(f);
  return c.u;
}

__device__ __forceinline__ uint4 pack8(float4 a, float4 b) {
  union { unsigned short us[8]; uint4 u; } r;
  r.us[0] = f2bf(a.x); r.us[1] = f2bf(a.y); r.us[2] = f2bf(a.z); r.us[3] = f2bf(a.w);
  r.us[4] = f2bf(b.x); r.us[5] = f2bf(b.y); r.us[6] = f2bf(b.z); r.us[7] = f2bf(b.w);
  return r.u;
}

// ---------------- edge-MLP -> exact PWL tables (1 block, 256 threads) ----------------
// f_h(e) = sum_k We2[k,h]*relu(e*w1[k]+b1[k]) + be2[h] is PWL with breakpoints t_k=-b1/w1.
__device__ void prep_block(const MegaArgs& a, char* smem) {
  float* sT   = (float*)smem;                      // 2048
  int*   sIdx = (int*)(smem + 2048);               // 2048
  float (*sDA)[8] = (float (*)[8])(smem + 4096);   // 16384
  float (*sDC)[8] = (float (*)[8])(smem + 20480);  // 16384
  float* sA0 = (float*)(smem + 36864);             // 32
  float* sC0 = (float*)(smem + 36896);             // 32
  int tid = threadIdx.x;
  for (int p = tid; p < 512; p += 256) {
    float w = a.w1[p], bb = a.b1[p];
    sT[p] = (w != 0.f) ? (-bb / w) : -3.4e38f;  // w==0: never a real crossing
    sIdx[p] = p;
#pragma unroll
    for (int h = 0; h < 8; ++h) {
      float w2 = a.we2[p * 8 + h];
      float ra = 0.f, rc = 0.f;
      if (w < 0.f)       { ra = w2 * w; rc = w2 * bb; }
      else if (w == 0.f) { rc = w2 * fmaxf(bb, 0.f); }
      sDA[p][h] = ra; sDC[p][h] = rc;
    }
  }
  __syncthreads();
  // bitonic sort ascending: 256 compare-exchange pairs per substage
  for (int size = 2; size <= 512; size <<= 1) {
    for (int stride = size >> 1; stride > 0; stride >>= 1) {
      int p = tid;
      int i = ((p / stride) * (stride << 1)) + (p % stride);
      int j = i + stride;
      bool up = ((i & size) == 0);
      float ti = sT[i], tj = sT[j];
      if (up ? (ti > tj) : (ti < tj)) {
        sT[i] = tj; sT[j] = ti;
        int t = sIdx[i]; sIdx[i] = sIdx[j]; sIdx[j] = t;
      }
      __syncthreads();
    }
  }
  // tree-reduce seg0 contributions
#pragma unroll
  for (int h = 0; h < 8; ++h) { sDA[tid][h] += sDA[tid + 256][h]; sDC[tid][h] += sDC[tid + 256][h]; }
  __syncthreads();
  for (int st = 128; st > 0; st >>= 1) {
    if (tid < st) {
#pragma unroll
      for (int h = 0; h < 8; ++h) { sDA[tid][h] += sDA[tid + st][h]; sDC[tid][h] += sDC[tid + st][h]; }
    }
    __syncthreads();
  }
  if (tid < 8) { sA0[tid] = sDA[0][tid]; sC0[tid] = sDC[0][tid] + a.be2[tid]; }
  __syncthreads();
  // per-sorted-position deltas
  for (int p = tid; p < 512; p += 256) {
    int k = sIdx[p];
    float wk = a.w1[k], bk2 = a.b1[k];
#pragma unroll
    for (int h = 0; h < 8; ++h) {
      float w2 = a.we2[k * 8 + h];
      float da = 0.f, dc = 0.f;
      if (wk > 0.f)      { da =  w2 * wk; dc =  w2 * bk2; }
      else if (wk < 0.f) { da = -w2 * wk; dc = -w2 * bk2; }
      sDA[p][h] = da; sDC[p][h] = dc;
    }
  }
  __syncthreads();
  // inclusive Hillis-Steele scan over 512 sorted positions, 2 per thread
  for (int off = 1; off < 512; off <<= 1) {
    float ra[2][8], rc[2][8];
#pragma unroll
    for (int e = 0; e < 2; ++e) {
      int p = tid + e * 256;
      if (p >= off) {
#pragma unroll
        for (int h = 0; h < 8; ++h) { ra[e][h] = sDA[p - off][h]; rc[e][h] = sDC[p - off][h]; }
      }
    }
    __syncthreads();
#pragma unroll
    for (int e = 0; e < 2; ++e) {
      int p = tid + e * 256;
      if (p >= off) {
#pragma unroll
        for (int h = 0; h < 8; ++h) { sDA[p][h] += ra[e][h]; sDC[p][h] += rc[e][h]; }
      }
    }
    __syncthreads();
  }
  a.wsT[tid] = sT[tid]; a.wsT[tid + 256] = sT[tid + 256];
  if (tid < 8) { a.wsA[tid * 513] = sA0[tid]; a.wsC[tid * 513] = sC0[tid]; }
  for (int p = tid; p < 512; p += 256) {
#pragma unroll
    for (int h = 0; h < 8; ++h) {
      a.wsA[h * 513 + p + 1] = sA0[h] + sDA[p][h];
      a.wsC[h * 513 + p + 1] = sC0[h] + sDC[p][h];
    }
  }
}

// ---------------- bf16 MFMA GEMM tile with in-staging fp32 convert/transpose ----------
// A: fp32 (Af) or bf16 (Ab), row-major [M][512]. W: fp32 [512][N] row-major, transposed
// to bf16 during LDS staging with k-slot XOR swizzle (kb8' = kb8 ^ (n>>4)) to break the
// structural 8-way bank conflict. Y = A @ W + bias (64x64 tile, K=512).
__device__ void gemm_core(const float* __restrict__ Af, const unsigned short* __restrict__ Ab,
                          const float* __restrict__ W, const float* __restrict__ bias,
                          void* out, int mode, int m0, int n0, char* smem) {
  unsigned short (*sA)[72]  = (unsigned short (*)[72])smem;
  unsigned short (*sBt)[72] = (unsigned short (*)[72])(smem + 9216);
  int tid = threadIdx.x, wave = tid >> 6, lane = tid & 63;
  int quad = lane >> 4, l16 = lane & 15;
  f32x4 acc[4] = {{0.f,0.f,0.f,0.f},{0.f,0.f,0.f,0.f},{0.f,0.f,0.f,0.f},{0.f,0.f,0.f,0.f}};
  int lr = tid >> 2, ls = tid & 3;
  int kb8 = lr >> 3, klo = lr & 7;            // k-slot decomposition for the W swizzle
  for (int kb = 0; kb < 512; kb += 64) {
    __syncthreads();
    if (Af) {
      const float4* ap = (const float4*)(Af + (size_t)(m0 + lr) * 512 + kb + ls * 16);
      float4 v0 = ap[0], v1 = ap[1], v2 = ap[2], v3 = ap[3];
      *(uint4*)&sA[lr][ls * 16]     = pack8(v0, v1);
      *(uint4*)&sA[lr][ls * 16 + 8] = pack8(v2, v3);
    } else {
      *(uint4*)&sA[lr][ls * 16]     = *(const uint4*)(Ab + (size_t)(m0 + lr) * 512 + kb + ls * 16);
      *(uint4*)&sA[lr][ls * 16 + 8] = *(const uint4*)(Ab + (size_t)(m0 + lr) * 512 + kb + ls * 16 + 8);
    }
    {
      // W[kb+lr][n0+ls*16 .. +16] fp32 -> sBt[n][swizzled k] bf16
      const float4* wp = (const float4*)(W + (size_t)(kb + lr) * 512 + n0 + ls * 16);
      float4 w0 = wp[0], w1 = wp[1], w2 = wp[2], w3 = wp[3];
      int nb = ls * 16;
      // slot(n) = (kb8 ^ (n>>4))*8 + klo ; n>>4 == ls here
      int slot = ((kb8 ^ ls) << 3) + klo;
      sBt[nb + 0][slot] = f2bf(w0.x);  sBt[nb + 1][slot] = f2bf(w0.y);
      sBt[nb + 2][slot] = f2bf(w0.z);  sBt[nb + 3][slot] = f2bf(w0.w);
      sBt[nb + 4][slot] = f2bf(w1.x);  sBt[nb + 5][slot] = f2bf(w1.y);
      sBt[nb + 6][slot] = f2bf(w1.z);  sBt[nb + 7][slot] = f2bf(w1.w);
      sBt[nb + 8][slot] = f2bf(w2.x);  sBt[nb + 9][slot] = f2bf(w2.y);
      sBt[nb + 10][slot] = f2bf(w2.z); sBt[nb + 11][slot] = f2bf(w2.w);
      sBt[nb + 12][slot] = f2bf(w3.x); sBt[nb + 13][slot] = f2bf(w3.y);
      sBt[nb + 14][slot] = f2bf(w3.z); sBt[nb + 15][slot] = f2bf(w3.w);
    }
    __syncthreads();
    for (int ks = 0; ks < 2; ++ks) {
      bf16x8 af = *(const bf16x8*)&sA[wave * 16 + l16][ks * 32 + quad * 8];
#pragma unroll
      for (int nt = 0; nt < 4; ++nt) {
        // un-swizzle: kb8 = ks*4+quad, n>>4 = nt
        bf16x8 bf = *(const bf16x8*)&sBt[nt * 16 + l16][((ks * 4 + quad) ^ nt) * 8];
        acc[nt] = __builtin_amdgcn_mfma_f32_16x16x32_bf16(af, bf, acc[nt], 0, 0, 0);
      }
    }
  }
  int mbase = m0 + wave * 16 + quad * 4;  // C row = quad*4+reg (m89-verified)
#pragma unroll
  for (int nt = 0; nt < 4; ++nt) {
    int n = n0 + nt * 16 + l16;
    float bv = bias[n];
#pragma unroll
    for (int r = 0; r < 4; ++r) {
      float v = acc[nt][r] + bv;
      int m = mbase + r;
      if (mode == 0) {
        int b = m >> 9, l = m & 511, hh = n >> 6, d = n & 63;
        ((unsigned short*)out)[(((size_t)(b * 8 + hh) * 512) + l) * 64 + d] = f2bf(v);
      } else if (mode == 1) {
        ((float*)out)[(size_t)m * 512 + n] = v;
      } else {
        int b = m >> 9, l = m & 511, hh = n >> 6, d = n & 63;
        ((unsigned short*)out)[(((size_t)(b * 8 + hh) * 64) + d) * 512 + l] = f2bf(v);
      }
    }
  }
}

// ---------------- fused edge-bias attention with inline PWL segment search ------------
// 16 q-rows/block, 4 waves split 512 keys (128 each), no barriers in the key math.
__device__ void attn_block(const MegaArgs& a, int qt, int h, int b, char* smem) {
  float* sT  = (float*)smem;                                            // 2048
  float* sAh = (float*)(smem + 2048);                                   // 2052
  float* sCh = (float*)(smem + 4100);                                   // 2052
  unsigned short (*sP)[16][40] = (unsigned short (*)[16][40])(smem + 6160);  // 5120
  float (*sO)[4][16][16] = (float (*)[4][16][16])(smem + 11280);        // 16384
  float (*sM)[16] = (float (*)[16])(smem + 27664);                      // 256
  float (*sL)[16] = (float (*)[16])(smem + 27920);                      // 256
  const unsigned short* Qb = a.wsb + QB_OFF;
  const unsigned short* Kb = a.wsb + KB_OFF;
  const unsigned short* Vt = a.wsb + VT_OFF;
  int bh = b * 8 + h;
  int q0 = qt * 16;
  int tid = threadIdx.x, wave = tid >> 6, lane = tid & 63;
  int quad = lane >> 4, l16 = lane & 15;
  sT[tid] = a.wsT[tid]; sT[tid + 256] = a.wsT[tid + 256];
  for (int i = tid; i < 513; i += 256) { sAh[i] = a.wsA[h * 513 + i]; sCh[i] = a.wsC[h * 513 + i]; }
  const unsigned short* qp = Qb + ((size_t)bh * 512 + q0 + l16) * 64 + quad * 8;
  bf16x8 qf0 = *(const bf16x8*)qp;
  bf16x8 qf1 = *(const bf16x8*)(qp + 32);
  int key_base = wave * 128;
  f32x4 S[4][2];
#pragma unroll
  for (int kt = 0; kt < 4; ++kt) {
    int key0 = key_base + kt * 32;
#pragma unroll
    for (int half = 0; half < 2; ++half) {
      const unsigned short* kp = Kb + ((size_t)bh * 512 + key0 + half * 16 + l16) * 64 + quad * 8;
      bf16x8 kf0 = *(const bf16x8*)kp;
      bf16x8 kf1 = *(const bf16x8*)(kp + 32);
      f32x4 acc = {0.f, 0.f, 0.f, 0.f};
      acc = __builtin_amdgcn_mfma_f32_16x16x32_bf16(qf0, kf0, acc, 0, 0, 0);
      acc = __builtin_amdgcn_mfma_f32_16x16x32_bf16(qf1, kf1, acc, 0, 0, 0);
      S[kt][half] = acc;
    }
  }
  __syncthreads();  // sT/sAh/sCh ready (placed after MFMA issue to overlap)
  // ---- scale + exact PWL edge bias; seg index via inline 9-step branchless search ----
#pragma unroll
  for (int kt = 0; kt < 4; ++kt)
#pragma unroll
    for (int half = 0; half < 2; ++half)
#pragma unroll
      for (int r = 0; r < 4; ++r) {
        int eidx = (b * 512 + q0 + quad * 4 + r) * 512 + key_base + kt * 32 + half * 16 + l16;
        float ev = a.eg[eidx];
        int lo = 0, hi = 512;
#pragma unroll
        for (int it = 0; it < 9; ++it) {  // count of sT[s] < ev (identical to seg pass)
          int mid = (lo + hi) >> 1;
          bool c = sT[mid] < ev;
          lo = c ? mid + 1 : lo;
          hi = c ? hi : mid;
        }
        S[kt][half][r] = S[kt][half][r] * 0.125f + sAh[lo] * ev + sCh[lo];
      }
  float m_w[4], l_w[4];
#pragma unroll
  for (int r = 0; r < 4; ++r) {
    float mx = -3.4e38f;
#pragma unroll
    for (int kt = 0; kt < 4; ++kt) { mx = fmaxf(mx, fmaxf(S[kt][0][r], S[kt][1][r])); }
    for (int off = 1; off < 16; off <<= 1) mx = fmaxf(mx, __shfl_xor(mx, off, 64));
    float s = 0.f;
#pragma unroll
    for (int kt = 0; kt < 4; ++kt)
#pragma unroll
      for (int half = 0; half < 2; ++half) {
        float p = exp2f((S[kt][half][r] - mx) * LOG2E);
        S[kt][half][r] = p; s += p;
      }
    for (int off = 1; off < 16; off <<= 1) s += __shfl_xor(s, off, 64);
    m_w[r] = mx; l_w[r] = s;
  }
  f32x4 Oacc[4] = {{0.f,0.f,0.f,0.f},{0.f,0.f,0.f,0.f},{0.f,0.f,0.f,0.f},{0.f,0.f,0.f,0.f}};
#pragma unroll
  for (int kt = 0; kt < 4; ++kt) {
    int key0 = key_base + kt * 32;
#pragma unroll
    for (int half = 0; half < 2; ++half)
#pragma unroll
      for (int r = 0; r < 4; ++r)
        sP[wave][quad * 4 + r][half * 16 + l16] = f2bf(S[kt][half][r]);
    __builtin_amdgcn_wave_barrier();  // wave-private LDS; compiler fence only
    bf16x8 pf = *(const bf16x8*)&sP[wave][l16][quad * 8];
    __builtin_amdgcn_wave_barrier();
#pragma unroll
    for (int nt = 0; nt < 4; ++nt) {
      bf16x8 vf = *(const bf16x8*)(Vt + ((size_t)bh * 64 + nt * 16 + l16) * 512 + key0 + quad * 8);
      Oacc[nt] = __builtin_amdgcn_mfma_f32_16x16x32_bf16(pf, vf, Oacc[nt], 0, 0, 0);
    }
  }
  if (l16 == 0) {
#pragma unroll
    for (int r = 0; r < 4; ++r) { sM[wave][quad * 4 + r] = m_w[r]; sL[wave][quad * 4 + r] = l_w[r]; }
  }
#pragma unroll
  for (int nt = 0; nt < 4; ++nt)
#pragma unroll
    for (int r = 0; r < 4; ++r)
      sO[wave][nt][quad * 4 + r][l16] = Oacc[nt][r];
  __syncthreads();
#pragma unroll
  for (int r = 0; r < 4; ++r) {
    int row = quad * 4 + r;
    float M = fmaxf(fmaxf(sM[0][row], sM[1][row]), fmaxf(sM[2][row], sM[3][row]));
    float L = 0.f, Ov = 0.f;
#pragma unroll
    for (int wv = 0; wv < 4; ++wv) {
      float f = exp2f((sM[wv][row] - M) * LOG2E);
      L += f * sL[wv][row];
      Ov += f * sO[wv][wave][row][l16];
    }
    float v = Ov / L;
    (a.wsb + AO_OFF)[((size_t)(b * 512 + q0 + row)) * 512 + h * 64 + wave * 16 + l16] = f2bf(v);
  }
}

// ---------------- launch 1: prep (block 0, independent) + QKV GEMM fp32-direct --------
__global__ __launch_bounds__(256) void k1(MegaArgs a) {
  __shared__ __align__(16) char smem[36928];
  int blk = blockIdx.x;
  if (blk == 0) {
    prep_block(a, smem);
  } else {
    int g = blk - 1, z = g >> 7, rem = g & 127;
    const float* A    = (z == 0) ? a.xq : (z == 1) ? a.xk : a.xv;
    const float* W    = (z == 0) ? a.wq : (z == 1) ? a.wk : a.wv;
    const float* bias = (z == 0) ? a.bq : (z == 1) ? a.bk : a.bv;
    void* outp = (void*)(a.wsb + ((z == 0) ? QB_OFF : (z == 1) ? KB_OFF : VT_OFF));
    gemm_core(A, nullptr, W, bias, outp, (z == 2) ? 2 : 0, (rem & 15) * 64, (rem >> 4) * 64, smem);
  }
}

// ---------------- launch 2: attention with inline seg search --------------------------
__global__ __launch_bounds__(256) void k2(MegaArgs a) {
  __shared__ __align__(16) char smem[28176];
  int blk = blockIdx.x;
  attn_block(a, blk & 31, (blk >> 5) & 7, blk >> 8, smem);
}

// ---------------- launch 3: output GEMM (fp32 Wo staged in-kernel) --------------------
__global__ __launch_bounds__(256) void k3(MegaArgs a) {
  __shared__ __align__(16) char smem[18432];
  gemm_core(nullptr, a.wsb + AO_OFF, a.wo, a.bo, (void*)a.out, 1,
            (blockIdx.x & 15) * 64, (blockIdx.x >> 4) * 64, smem);
}

extern "C" void kernel_launch(void* const* d_in, const int* in_sizes, int n_in,
                              void* d_out, int out_size, void* d_ws, size_t ws_size,
                              hipStream_t stream) {
  MegaArgs a;
  a.xq  = (const float*)d_in[0];
  a.xk  = (const float*)d_in[1];
  a.xv  = (const float*)d_in[2];
  a.eg  = (const float*)d_in[3];
  a.wq  = (const float*)d_in[4];
  a.bq  = (const float*)d_in[5];
  a.wk  = (const float*)d_in[6];
  a.bk  = (const float*)d_in[7];
  a.wv  = (const float*)d_in[8];
  a.bv  = (const float*)d_in[9];
  a.wo  = (const float*)d_in[10];
  a.bo  = (const float*)d_in[11];
  a.w1  = (const float*)d_in[12];
  a.b1  = (const float*)d_in[13];
  a.we2 = (const float*)d_in[14];
  a.be2 = (const float*)d_in[15];
  a.out = (float*)d_out;
  a.wsb = (unsigned short*)d_ws;
  a.wsT = (float*)((char*)d_ws + T_B);
  a.wsA = (float*)((char*)d_ws + A_B);
  a.wsC = (float*)((char*)d_ws + C_B);

  k1<<<385, 256, 0, stream>>>(a);
  k2<<<512, 256, 0, stream>>>(a);
  k3<<<128, 256, 0, stream>>>(a);
}

// Round 9
// 136.501 us; speedup vs baseline: 2.4825x; 1.0203x over previous
//
#include <hip/hip_runtime.h>
#include <hip/hip_bf16.h>

typedef __attribute__((ext_vector_type(8))) short bf16x8;
typedef __attribute__((ext_vector_type(4))) float f32x4;

#define LOG2E 1.44269504088896340736f

// ---- workspace layout ----
// bf16 element offsets
#define QB_OFF 2621440
#define KB_OFF 3145728
#define VT_OFF 3670016
#define AO_OFF 4194304
// byte offsets (fp32 tables)
#define T_B   9437184
#define A_B   (T_B + 4096)
#define C_B   (A_B + 20480)

struct MegaArgs {
  const float *xq, *xk, *xv, *eg;
  const float *wq, *wk, *wv, *wo;
  const float *bq, *bk, *bv, *bo;
  const float *w1, *b1, *we2, *be2;
  float* out;
  unsigned short* wsb;
  float *wsT, *wsA, *wsC;   // deduped: wsT[0..nu) breakpoints, (int)wsT[512]=nu,
                            // wsA/wsC [h*513 + c] for c in [0, nu]
};

__device__ __forceinline__ unsigned short f2bf(float f) {
  union { __hip_bfloat16 h; unsigned short u; } c;
  c.h = __float2bfloat16(f);
  return c.u;
}

__device__ __forceinline__ uint4 pack8(float4 a, float4 b) {
  union { unsigned short us[8]; uint4 u; } r;
  r.us[0] = f2bf(a.x); r.us[1] = f2bf(a.y); r.us[2] = f2bf(a.z); r.us[3] = f2bf(a.w);
  r.us[4] = f2bf(b.x); r.us[5] = f2bf(b.y); r.us[6] = f2bf(b.z); r.us[7] = f2bf(b.w);
  return r.u;
}

// ---------------- edge-MLP -> exact PWL tables, deduped (1 block, 256 threads) --------
// f_h(e) = sum_k We2[k,h]*relu(e*w1[k]+b1[k]) + be2[h] is PWL with breakpoints t_k=-b1/w1.
// Output: unique sorted breakpoints T' (nu of them) + per-head segment coeffs A''/C''
// at the nu+1 segments. Exact: A''[c] = full-table value at cumulative-count position.
__device__ void prep_block(const MegaArgs& a, char* smem) {
  float* sT   = (float*)smem;                      // 2048
  int*   sIdx = (int*)(smem + 2048);               // 2048 (reused as dedupe totals)
  float (*sDA)[8] = (float (*)[8])(smem + 4096);   // 16384 (rows 0-3 reused as reduce scratch)
  float (*sDC)[8] = (float (*)[8])(smem + 20480);  // 16384
  float* sA0 = (float*)(smem + 36864);             // 32
  float* sC0 = (float*)(smem + 36896);             // 32
  int tid = threadIdx.x, lane = tid & 63, w = tid >> 6;
  // init: breakpoints + seg-0 contributions kept in registers
  float accA[8] = {0,0,0,0,0,0,0,0}, accC[8] = {0,0,0,0,0,0,0,0};
  for (int e = 0; e < 2; ++e) {
    int p = tid + e * 256;
    float ww = a.w1[p], bb = a.b1[p];
    sT[p] = (ww != 0.f) ? (-bb / ww) : -3.4e38f;  // w==0: never a real crossing
    sIdx[p] = p;
#pragma unroll
    for (int h = 0; h < 8; ++h) {
      float w2 = a.we2[p * 8 + h];
      if (ww < 0.f)       { accA[h] += w2 * ww; accC[h] += w2 * bb; }
      else if (ww == 0.f) { accC[h] += w2 * fmaxf(bb, 0.f); }
    }
  }
  __syncthreads();
  // bitonic sort ascending; stride<64 substages are wave-local (128-elem windows)
  for (int size = 2; size <= 512; size <<= 1) {
    for (int stride = size >> 1; stride > 0; stride >>= 1) {
      if (size >= 256 && stride >= 64) __syncthreads();
      else __builtin_amdgcn_wave_barrier();
      int p = tid;
      int i = ((p / stride) * (stride << 1)) + (p % stride);
      int j = i + stride;
      bool up = ((i & size) == 0);
      float ti = sT[i], tj = sT[j];
      if (up ? (ti > tj) : (ti < tj)) {
        sT[i] = tj; sT[j] = ti;
        int t = sIdx[i]; sIdx[i] = sIdx[j]; sIdx[j] = t;
      }
    }
  }
  // seg-0 reduce via shuffle-xor (no barriers), 4 wave partials -> LDS
  for (int off = 32; off > 0; off >>= 1) {
#pragma unroll
    for (int h = 0; h < 8; ++h) {
      accA[h] += __shfl_xor(accA[h], off);
      accC[h] += __shfl_xor(accC[h], off);
    }
  }
  if (lane == 0) {
#pragma unroll
    for (int h = 0; h < 8; ++h) { sDA[w][h] = accA[h]; sDC[w][h] = accC[h]; }
  }
  __syncthreads();   // sort results + reduce partials visible
  if (tid < 8) {
    sA0[tid] = sDA[0][tid] + sDA[1][tid] + sDA[2][tid] + sDA[3][tid];
    sC0[tid] = sDC[0][tid] + sDC[1][tid] + sDC[2][tid] + sDC[3][tid] + a.be2[tid];
  }
  __syncthreads();   // sA0/sC0 ready before deltas overwrite sDA rows
  // per-sorted-position deltas
  for (int e = 0; e < 2; ++e) {
    int p = tid + e * 256;
    int k = sIdx[p];
    float wk = a.w1[k], bk2 = a.b1[k];
#pragma unroll
    for (int h = 0; h < 8; ++h) {
      float w2 = a.we2[k * 8 + h];
      float da = 0.f, dc = 0.f;
      if (wk > 0.f)      { da =  w2 * wk; dc =  w2 * bk2; }
      else if (wk < 0.f) { da = -w2 * wk; dc = -w2 * bk2; }
      sDA[p][h] = da; sDC[p][h] = dc;
    }
  }
  __syncthreads();
  // inclusive Hillis-Steele scan over 512 sorted positions, 2 per thread
  for (int off = 1; off < 512; off <<= 1) {
    float ra[2][8], rc[2][8];
#pragma unroll
    for (int e = 0; e < 2; ++e) {
      int p = tid + e * 256;
      if (p >= off) {
#pragma unroll
        for (int h = 0; h < 8; ++h) { ra[e][h] = sDA[p - off][h]; rc[e][h] = sDC[p - off][h]; }
      }
    }
    __syncthreads();
#pragma unroll
    for (int e = 0; e < 2; ++e) {
      int p = tid + e * 256;
      if (p >= off) {
#pragma unroll
        for (int h = 0; h < 8; ++h) { sDA[p][h] += ra[e][h]; sDC[p][h] += rc[e][h]; }
      }
    }
    __syncthreads();
  }
  // dedupe: ballot ranks of run starts; emit T' + segment coeffs at run boundaries
  bool n0 = (tid == 0) || (sT[tid] != sT[tid - 1]);
  bool n1 = (sT[tid + 256] != sT[tid + 255]);
  unsigned long long m0 = __ballot(n0), m1 = __ballot(n1);
  unsigned long long below = (1ull << lane) - 1ull;
  int loc0 = __popcll(m0 & below), loc1 = __popcll(m1 & below);
  int* tot = sIdx;  // sIdx dead after deltas; 8-int scratch
  if (lane == 0) { tot[w] = __popcll(m0); tot[4 + w] = __popcll(m1); }
  __syncthreads();
  int t[8];
#pragma unroll
  for (int j = 0; j < 8; ++j) t[j] = tot[j];
  int nuniq = t[0] + t[1] + t[2] + t[3] + t[4] + t[5] + t[6] + t[7];
  int off0 = 0, off1 = t[0] + t[1] + t[2] + t[3];
  for (int j = 0; j < 4; ++j) {
    if (j < w) { off0 += t[j]; off1 += t[4 + j]; }
  }
  if (n0) {
    int u = off0 + loc0;
    a.wsT[u] = sT[tid];
    if (tid == 0) {
#pragma unroll
      for (int h = 0; h < 8; ++h) { a.wsA[h * 513] = sA0[h]; a.wsC[h * 513] = sC0[h]; }
    } else {
#pragma unroll
      for (int h = 0; h < 8; ++h) {
        a.wsA[h * 513 + u] = sA0[h] + sDA[tid - 1][h];
        a.wsC[h * 513 + u] = sC0[h] + sDC[tid - 1][h];
      }
    }
  }
  if (n1) {
    int u = off1 + loc1;
    a.wsT[u] = sT[tid + 256];
#pragma unroll
    for (int h = 0; h < 8; ++h) {
      a.wsA[h * 513 + u] = sA0[h] + sDA[tid + 255][h];
      a.wsC[h * 513 + u] = sC0[h] + sDC[tid + 255][h];
    }
  }
  if (tid == 0) {
#pragma unroll
    for (int h = 0; h < 8; ++h) {
      a.wsA[h * 513 + nuniq] = sA0[h] + sDA[511][h];
      a.wsC[h * 513 + nuniq] = sC0[h] + sDC[511][h];
    }
    *(int*)(a.wsT + 512) = nuniq;
  }
}

// ---------------- bf16 MFMA GEMM tile with in-staging fp32 convert/transpose ----------
// A: fp32 (Af) or bf16 (Ab), row-major [M][512]. W: fp32 [512][N] row-major, transposed
// to bf16 during LDS staging with k-slot XOR swizzle. Y = A @ W + bias (64x64, K=512).
__device__ void gemm_core(const float* __restrict__ Af, const unsigned short* __restrict__ Ab,
                          const float* __restrict__ W, const float* __restrict__ bias,
                          void* out, int mode, int m0, int n0, char* smem) {
  unsigned short (*sA)[72]  = (unsigned short (*)[72])smem;
  unsigned short (*sBt)[72] = (unsigned short (*)[72])(smem + 9216);
  int tid = threadIdx.x, wave = tid >> 6, lane = tid & 63;
  int quad = lane >> 4, l16 = lane & 15;
  f32x4 acc[4] = {{0.f,0.f,0.f,0.f},{0.f,0.f,0.f,0.f},{0.f,0.f,0.f,0.f},{0.f,0.f,0.f,0.f}};
  int lr = tid >> 2, ls = tid & 3;
  int kb8 = lr >> 3, klo = lr & 7;
  for (int kb = 0; kb < 512; kb += 64) {
    __syncthreads();
    if (Af) {
      const float4* ap = (const float4*)(Af + (size_t)(m0 + lr) * 512 + kb + ls * 16);
      float4 v0 = ap[0], v1 = ap[1], v2 = ap[2], v3 = ap[3];
      *(uint4*)&sA[lr][ls * 16]     = pack8(v0, v1);
      *(uint4*)&sA[lr][ls * 16 + 8] = pack8(v2, v3);
    } else {
      *(uint4*)&sA[lr][ls * 16]     = *(const uint4*)(Ab + (size_t)(m0 + lr) * 512 + kb + ls * 16);
      *(uint4*)&sA[lr][ls * 16 + 8] = *(const uint4*)(Ab + (size_t)(m0 + lr) * 512 + kb + ls * 16 + 8);
    }
    {
      const float4* wp = (const float4*)(W + (size_t)(kb + lr) * 512 + n0 + ls * 16);
      float4 w0 = wp[0], w1 = wp[1], w2 = wp[2], w3 = wp[3];
      int nb = ls * 16;
      int slot = ((kb8 ^ ls) << 3) + klo;   // k-slot XOR swizzle breaks 8-way conflict
      sBt[nb + 0][slot] = f2bf(w0.x);  sBt[nb + 1][slot] = f2bf(w0.y);
      sBt[nb + 2][slot] = f2bf(w0.z);  sBt[nb + 3][slot] = f2bf(w0.w);
      sBt[nb + 4][slot] = f2bf(w1.x);  sBt[nb + 5][slot] = f2bf(w1.y);
      sBt[nb + 6][slot] = f2bf(w1.z);  sBt[nb + 7][slot] = f2bf(w1.w);
      sBt[nb + 8][slot] = f2bf(w2.x);  sBt[nb + 9][slot] = f2bf(w2.y);
      sBt[nb + 10][slot] = f2bf(w2.z); sBt[nb + 11][slot] = f2bf(w2.w);
      sBt[nb + 12][slot] = f2bf(w3.x); sBt[nb + 13][slot] = f2bf(w3.y);
      sBt[nb + 14][slot] = f2bf(w3.z); sBt[nb + 15][slot] = f2bf(w3.w);
    }
    __syncthreads();
    for (int ks = 0; ks < 2; ++ks) {
      bf16x8 af = *(const bf16x8*)&sA[wave * 16 + l16][ks * 32 + quad * 8];
#pragma unroll
      for (int nt = 0; nt < 4; ++nt) {
        bf16x8 bf = *(const bf16x8*)&sBt[nt * 16 + l16][((ks * 4 + quad) ^ nt) * 8];
        acc[nt] = __builtin_amdgcn_mfma_f32_16x16x32_bf16(af, bf, acc[nt], 0, 0, 0);
      }
    }
  }
  int mbase = m0 + wave * 16 + quad * 4;  // C row = quad*4+reg (m89-verified)
#pragma unroll
  for (int nt = 0; nt < 4; ++nt) {
    int n = n0 + nt * 16 + l16;
    float bv = bias[n];
#pragma unroll
    for (int r = 0; r < 4; ++r) {
      float v = acc[nt][r] + bv;
      int m = mbase + r;
      if (mode == 0) {
        int b = m >> 9, l = m & 511, hh = n >> 6, d = n & 63;
        ((unsigned short*)out)[(((size_t)(b * 8 + hh) * 512) + l) * 64 + d] = f2bf(v);
      } else if (mode == 1) {
        ((float*)out)[(size_t)m * 512 + n] = v;
      } else {
        int b = m >> 9, l = m & 511, hh = n >> 6, d = n & 63;
        ((unsigned short*)out)[(((size_t)(b * 8 + hh) * 64) + d) * 512 + l] = f2bf(v);
      }
    }
  }
}

// ---------------- fused edge-bias attention, deduped inline segment search ------------
__device__ void attn_block(const MegaArgs& a, int qt, int h, int b, char* smem) {
  float* sT  = (float*)smem;                                            // up to 2048
  float* sAh = (float*)(smem + 2048);                                   // up to 2052
  float* sCh = (float*)(smem + 4100);                                   // up to 2052
  unsigned short (*sP)[16][40] = (unsigned short (*)[16][40])(smem + 6160);  // 5120
  float (*sO)[4][16][16] = (float (*)[4][16][16])(smem + 11280);        // 16384
  float (*sM)[16] = (float (*)[16])(smem + 27664);                      // 256
  float (*sL)[16] = (float (*)[16])(smem + 27920);                      // 256
  const unsigned short* Qb = a.wsb + QB_OFF;
  const unsigned short* Kb = a.wsb + KB_OFF;
  const unsigned short* Vt = a.wsb + VT_OFF;
  int bh = b * 8 + h;
  int q0 = qt * 16;
  int tid = threadIdx.x, wave = tid >> 6, lane = tid & 63;
  int quad = lane >> 4, l16 = lane & 15;
  int nu = *(const int*)(a.wsT + 512);   // unique breakpoint count
  for (int i = tid; i < nu; i += 256) sT[i] = a.wsT[i];
  for (int i = tid; i <= nu; i += 256) { sAh[i] = a.wsA[h * 513 + i]; sCh[i] = a.wsC[h * 513 + i]; }
  const unsigned short* qp = Qb + ((size_t)bh * 512 + q0 + l16) * 64 + quad * 8;
  bf16x8 qf0 = *(const bf16x8*)qp;
  bf16x8 qf1 = *(const bf16x8*)(qp + 32);
  int key_base = wave * 128;
  f32x4 S[4][2];
#pragma unroll
  for (int kt = 0; kt < 4; ++kt) {
    int key0 = key_base + kt * 32;
#pragma unroll
    for (int half = 0; half < 2; ++half) {
      const unsigned short* kp = Kb + ((size_t)bh * 512 + key0 + half * 16 + l16) * 64 + quad * 8;
      bf16x8 kf0 = *(const bf16x8*)kp;
      bf16x8 kf1 = *(const bf16x8*)(kp + 32);
      f32x4 acc = {0.f, 0.f, 0.f, 0.f};
      acc = __builtin_amdgcn_mfma_f32_16x16x32_bf16(qf0, kf0, acc, 0, 0, 0);
      acc = __builtin_amdgcn_mfma_f32_16x16x32_bf16(qf1, kf1, acc, 0, 0, 0);
      S[kt][half] = acc;
    }
  }
  __syncthreads();  // sT/sAh/sCh ready (placed after MFMA issue to overlap)
  // scale + exact PWL edge bias; segment via short search over nu uniques
#pragma unroll
  for (int kt = 0; kt < 4; ++kt)
#pragma unroll
    for (int half = 0; half < 2; ++half)
#pragma unroll
      for (int r = 0; r < 4; ++r) {
        int eidx = (b * 512 + q0 + quad * 4 + r) * 512 + key_base + kt * 32 + half * 16 + l16;
        float ev = a.eg[eidx];
        int lo = 0, hi = nu;
        while (lo < hi) {   // count of T'[s] < ev; ~log2(nu) iterations
          int mid = (lo + hi) >> 1;
          bool c = sT[mid] < ev;
          lo = c ? mid + 1 : lo;
          hi = c ? hi : mid;
        }
        S[kt][half][r] = S[kt][half][r] * 0.125f + sAh[lo] * ev + sCh[lo];
      }
  float m_w[4], l_w[4];
#pragma unroll
  for (int r = 0; r < 4; ++r) {
    float mx = -3.4e38f;
#pragma unroll
    for (int kt = 0; kt < 4; ++kt) { mx = fmaxf(mx, fmaxf(S[kt][0][r], S[kt][1][r])); }
    for (int off = 1; off < 16; off <<= 1) mx = fmaxf(mx, __shfl_xor(mx, off, 64));
    float s = 0.f;
#pragma unroll
    for (int kt = 0; kt < 4; ++kt)
#pragma unroll
      for (int half = 0; half < 2; ++half) {
        float p = exp2f((S[kt][half][r] - mx) * LOG2E);
        S[kt][half][r] = p; s += p;
      }
    for (int off = 1; off < 16; off <<= 1) s += __shfl_xor(s, off, 64);
    m_w[r] = mx; l_w[r] = s;
  }
  f32x4 Oacc[4] = {{0.f,0.f,0.f,0.f},{0.f,0.f,0.f,0.f},{0.f,0.f,0.f,0.f},{0.f,0.f,0.f,0.f}};
#pragma unroll
  for (int kt = 0; kt < 4; ++kt) {
    int key0 = key_base + kt * 32;
#pragma unroll
    for (int half = 0; half < 2; ++half)
#pragma unroll
      for (int r = 0; r < 4; ++r)
        sP[wave][quad * 4 + r][half * 16 + l16] = f2bf(S[kt][half][r]);
    __builtin_amdgcn_wave_barrier();  // wave-private LDS; compiler fence only
    bf16x8 pf = *(const bf16x8*)&sP[wave][l16][quad * 8];
    __builtin_amdgcn_wave_barrier();
#pragma unroll
    for (int nt = 0; nt < 4; ++nt) {
      bf16x8 vf = *(const bf16x8*)(Vt + ((size_t)bh * 64 + nt * 16 + l16) * 512 + key0 + quad * 8);
      Oacc[nt] = __builtin_amdgcn_mfma_f32_16x16x32_bf16(pf, vf, Oacc[nt], 0, 0, 0);
    }
  }
  if (l16 == 0) {
#pragma unroll
    for (int r = 0; r < 4; ++r) { sM[wave][quad * 4 + r] = m_w[r]; sL[wave][quad * 4 + r] = l_w[r]; }
  }
#pragma unroll
  for (int nt = 0; nt < 4; ++nt)
#pragma unroll
    for (int r = 0; r < 4; ++r)
      sO[wave][nt][quad * 4 + r][l16] = Oacc[nt][r];
  __syncthreads();
#pragma unroll
  for (int r = 0; r < 4; ++r) {
    int row = quad * 4 + r;
    float M = fmaxf(fmaxf(sM[0][row], sM[1][row]), fmaxf(sM[2][row], sM[3][row]));
    float L = 0.f, Ov = 0.f;
#pragma unroll
    for (int wv = 0; wv < 4; ++wv) {
      float f = exp2f((sM[wv][row] - M) * LOG2E);
      L += f * sL[wv][row];
      Ov += f * sO[wv][wave][row][l16];
    }
    float v = Ov / L;
    (a.wsb + AO_OFF)[((size_t)(b * 512 + q0 + row)) * 512 + h * 64 + wave * 16 + l16] = f2bf(v);
  }
}

// ---------------- launch 1: prep (block 0, independent) + QKV GEMM fp32-direct --------
__global__ __launch_bounds__(256) void k1(MegaArgs a) {
  __shared__ __align__(16) char smem[36928];
  int blk = blockIdx.x;
  if (blk == 0) {
    prep_block(a, smem);
  } else {
    int g = blk - 1, z = g >> 7, rem = g & 127;
    const float* A    = (z == 0) ? a.xq : (z == 1) ? a.xk : a.xv;
    const float* W    = (z == 0) ? a.wq : (z == 1) ? a.wk : a.wv;
    const float* bias = (z == 0) ? a.bq : (z == 1) ? a.bk : a.bv;
    void* outp = (void*)(a.wsb + ((z == 0) ? QB_OFF : (z == 1) ? KB_OFF : VT_OFF));
    gemm_core(A, nullptr, W, bias, outp, (z == 2) ? 2 : 0, (rem & 15) * 64, (rem >> 4) * 64, smem);
  }
}

// ---------------- launch 2: attention with deduped inline seg search ------------------
__global__ __launch_bounds__(256) void k2(MegaArgs a) {
  __shared__ __align__(16) char smem[28176];
  int blk = blockIdx.x;
  attn_block(a, blk & 31, (blk >> 5) & 7, blk >> 8, smem);
}

// ---------------- launch 3: output GEMM (fp32 Wo staged in-kernel) --------------------
__global__ __launch_bounds__(256) void k3(MegaArgs a) {
  __shared__ __align__(16) char smem[18432];
  gemm_core(nullptr, a.wsb + AO_OFF, a.wo, a.bo, (void*)a.out, 1,
            (blockIdx.x & 15) * 64, (blockIdx.x >> 4) * 64, smem);
}

extern "C" void kernel_launch(void* const* d_in, const int* in_sizes, int n_in,
                              void* d_out, int out_size, void* d_ws, size_t ws_size,
                              hipStream_t stream) {
  MegaArgs a;
  a.xq  = (const float*)d_in[0];
  a.xk  = (const float*)d_in[1];
  a.xv  = (const float*)d_in[2];
  a.eg  = (const float*)d_in[3];
  a.wq  = (const float*)d_in[4];
  a.bq  = (const float*)d_in[5];
  a.wk  = (const float*)d_in[6];
  a.bk  = (const float*)d_in[7];
  a.wv  = (const float*)d_in[8];
  a.bv  = (const float*)d_in[9];
  a.wo  = (const float*)d_in[10];
  a.bo  = (const float*)d_in[11];
  a.w1  = (const float*)d_in[12];
  a.b1  = (const float*)d_in[13];
  a.we2 = (const float*)d_in[14];
  a.be2 = (const float*)d_in[15];
  a.out = (float*)d_out;
  a.wsb = (unsigned short*)d_ws;
  a.wsT = (float*)((char*)d_ws + T_B);
  a.wsA = (float*)((char*)d_ws + A_B);
  a.wsC = (float*)((char*)d_ws + C_B);

  k1<<<385, 256, 0, stream>>>(a);
  k2<<<512, 256, 0, stream>>>(a);
  k3<<<128, 256, 0, stream>>>(a);
}